// Round 9
// baseline (281.349 us; speedup 1.0000x reference)
//
#include <hip/hip_runtime.h>
#include <cstdint>

#define T_TOK 16384   // B*S = 8*2048
#define D     512
#define E     8

typedef __attribute__((ext_vector_type(4))) float f32x4;
typedef __attribute__((ext_vector_type(8))) short short8v;

__device__ __forceinline__ unsigned short f2bf(float f) {
    unsigned u = __float_as_uint(f);
    u += 0x7FFF + ((u >> 16) & 1);          // RNE
    return (unsigned short)(u >> 16);
}
__device__ __forceinline__ float bf2f(unsigned short h) {
    return __uint_as_float((unsigned)h << 16);
}
// 16B-granule XOR swizzle inside a 64B LDS row (read side; involution)
__device__ __forceinline__ int swz(int r, int g) {
    return (r << 6) + (((g ^ ((r >> 1) & 3)) & 3) << 4);
}
// async global->LDS, 16B/lane, dest = wave-uniform base + lane*16
__device__ __forceinline__ void gload16(const void* g, void* s) {
    __builtin_amdgcn_global_load_lds(
        (const __attribute__((address_space(1))) unsigned int*)g,
        (__attribute__((address_space(3))) unsigned int*)s, 16, 0, 0);
}

// ---------------------------------------------------------------------------
// W1 -> bf16 hi/lo  (+ block 256 zeroes counts/embed; ws is 0xAA-poisoned)
// ---------------------------------------------------------------------------
__global__ __launch_bounds__(256) void k_conv_w1(const float* __restrict__ W,
                                                 unsigned short* __restrict__ hi,
                                                 unsigned short* __restrict__ lo,
                                                 int* __restrict__ c2,
                                                 int* __restrict__ c3,
                                                 float* __restrict__ embed)
{
    const int tid = threadIdx.x;
    if (blockIdx.x == 256) {
        if (tid < E) { c2[tid] = 0; c3[tid] = 0; }
        for (int i = tid; i < 8 * D; i += 256) embed[i] = 0.f;
        return;
    }
    const int i = (blockIdx.x * 256 + tid) * 4;
    const float4 v = *(const float4*)(W + i);
    const float f[4] = {v.x, v.y, v.z, v.w};
    unsigned short h[4], l[4];
#pragma unroll
    for (int j = 0; j < 4; ++j) {
        h[j] = f2bf(f[j]);
        l[j] = f2bf(f[j] - bf2f(h[j]));
    }
    *(uint2*)(hi + i) = *(uint2*)h;
    *(uint2*)(lo + i) = *(uint2*)l;
}

// ---------------------------------------------------------------------------
// x -> bf16 hi/lo (moves layer-1 A-conversion off the GEMM critical path)
// ---------------------------------------------------------------------------
__global__ __launch_bounds__(256) void k_conv_x(const float* __restrict__ x,
                                                unsigned short* __restrict__ xh,
                                                unsigned short* __restrict__ xl)
{
    const size_t i = ((size_t)blockIdx.x * 256 + threadIdx.x) * 16;
    float f[16];
#pragma unroll
    for (int q = 0; q < 4; ++q)
        *(float4*)&f[q * 4] = *(const float4*)(x + i + q * 4);
    unsigned short h[16], l[16];
#pragma unroll
    for (int j = 0; j < 16; ++j) {
        h[j] = f2bf(f[j]);
        l[j] = f2bf(f[j] - bf2f(h[j]));
    }
    *(uint4*)(xh + i)     = *(uint4*)&h[0];
    *(uint4*)(xh + i + 8) = *(uint4*)&h[8];
    *(uint4*)(xl + i)     = *(uint4*)&l[0];
    *(uint4*)(xl + i + 8) = *(uint4*)&l[8];
}

// ---------------------------------------------------------------------------
// We[e][k][n] -> transposed bf16 hi/lo  WT[e][n][k]; uint2 stores
// ---------------------------------------------------------------------------
__global__ __launch_bounds__(256) void k_prep_we(const float* __restrict__ We2,
                                                 const float* __restrict__ We3,
                                                 unsigned short* __restrict__ hi2,
                                                 unsigned short* __restrict__ lo2,
                                                 unsigned short* __restrict__ hi3,
                                                 unsigned short* __restrict__ lo3)
{
    __shared__ float t[32][33];
    const int z = blockIdx.z;            // 0..15 : expert + 8*layer
    const int e = z & 7;
    const float* src = (z < 8 ? We2 : We3) + ((size_t)e << 18);
    unsigned short* dh = (z < 8 ? hi2 : hi3) + ((size_t)e << 18);
    unsigned short* dl = (z < 8 ? lo2 : lo3) + ((size_t)e << 18);
    const int k0 = blockIdx.x << 5, n0 = blockIdx.y << 5;
    const int tx = threadIdx.x & 31, ty = threadIdx.x >> 5;
#pragma unroll
    for (int i = 0; i < 32; i += 8)
        t[ty + i][tx] = src[(size_t)(k0 + ty + i) * D + n0 + tx];
    __syncthreads();
    const int n  = threadIdx.x >> 3;         // 0..31 out row (n)
    const int kc = (threadIdx.x & 7) << 2;   // 0..28 k chunk
    unsigned short h4[4], l4[4];
#pragma unroll
    for (int j = 0; j < 4; ++j) {
        const float f = t[kc + j][n];
        h4[j] = f2bf(f);
        l4[j] = f2bf(f - bf2f(h4[j]));
    }
    const size_t o = (size_t)(n0 + n) * D + k0 + kc;
    *(uint2*)(dh + o) = *(uint2*)h4;
    *(uint2*)(dl + o) = *(uint2*)l4;
}

// ---------------------------------------------------------------------------
// Gating (cooperative): 8 threads/token x 64 dims, 2 tokens per slot.
// ---------------------------------------------------------------------------
__global__ __launch_bounds__(256) void k_gating(const float* __restrict__ H,
                                                const float* __restrict__ gw,
                                                float* __restrict__ p,
                                                int* __restrict__ lists,
                                                int* __restrict__ counts)
{
    __shared__ float gws[D * E];          // 16 KB, [d][e]
    __shared__ int histo[E], basex[E];
    const int tid = threadIdx.x;
    for (int i = tid; i < D * E; i += 256) gws[i] = gw[i];
    if (tid < E) histo[tid] = 0;
    __syncthreads();

    const int part = tid & 7;             // 64-dim slice
    const int slot = tid >> 3;            // 0..31
    const int t0 = (blockIdx.x << 6) + slot;
    const int t1 = t0 + 32;
    const int d0 = part << 6;

    float a0[E], a1[E];
#pragma unroll
    for (int e = 0; e < E; ++e) { a0[e] = 0.f; a1[e] = 0.f; }
    const float* h0 = H + (size_t)t0 * D + d0;
    const float* h1 = H + (size_t)t1 * D + d0;
#pragma unroll 4
    for (int i = 0; i < 64; i += 4) {
        const float4 v0 = *(const float4*)(h0 + i);
        const float4 v1 = *(const float4*)(h1 + i);
        const float* gp = gws + (size_t)(d0 + i) * E;
#pragma unroll
        for (int j = 0; j < 4; ++j) {
            const f32x4 gA = *(const f32x4*)(gp + j * E);
            const f32x4 gB = *(const f32x4*)(gp + j * E + 4);
            const float x0 = (j == 0) ? v0.x : (j == 1) ? v0.y : (j == 2) ? v0.z : v0.w;
            const float x1 = (j == 0) ? v1.x : (j == 1) ? v1.y : (j == 2) ? v1.z : v1.w;
#pragma unroll
            for (int e = 0; e < 4; ++e) {
                a0[e]     += x0 * gA[e];
                a0[e + 4] += x0 * gB[e];
                a1[e]     += x1 * gA[e];
                a1[e + 4] += x1 * gB[e];
            }
        }
    }
#pragma unroll
    for (int e = 0; e < E; ++e) {
#pragma unroll
        for (int o = 1; o < 8; o <<= 1) {
            a0[e] += __shfl_xor(a0[e], o, 8);
            a1[e] += __shfl_xor(a1[e], o, 8);
        }
    }

    int mi0 = 0, mi1 = 0, r0 = 0, r1 = 0;
    if (part == 0) {
        float m0 = a0[0], m1 = a1[0];
#pragma unroll
        for (int e = 1; e < E; ++e) {      // strict > == argmax first-max
            if (a0[e] > m0) { m0 = a0[e]; mi0 = e; }
            if (a1[e] > m1) { m1 = a1[e]; mi1 = e; }
        }
        float s0 = 0.f, s1 = 0.f;
#pragma unroll
        for (int e = 0; e < E; ++e) { s0 += expf(a0[e] - m0); s1 += expf(a1[e] - m1); }
        p[t0] = 1.0f / s0;
        p[t1] = 1.0f / s1;
        r0 = atomicAdd(&histo[mi0], 1);
        r1 = atomicAdd(&histo[mi1], 1);
    }
    __syncthreads();
    if (tid < E) basex[tid] = atomicAdd(&counts[tid], histo[tid]);
    __syncthreads();
    if (part == 0) {
        lists[mi0 * T_TOK + basex[mi0] + r0] = t0;
        lists[mi1 * T_TOK + basex[mi1] + r1] = t1;
    }
}

// ---------------------------------------------------------------------------
// Split-bf16 MFMA GEMM: 128x128 tile, BK=32, 4 waves (2x2), 16x16x32 bf16.
// A is PRE-SPLIT bf16 hi/lo [t][k]; staging = global_load_lds width-16 with
// pre-swizzled source granule (XOR involution), LDS dest linear per wave.
// Read side / MFMA core / epilogue addressing identical to verified r3 kernel.
// OUTCONV epilogues additionally store hi/lo bf16 of the result (next A).
// ---------------------------------------------------------------------------
template <bool GATHER, bool OUTCONV>
__global__ __launch_bounds__(256, 2) void k_gemm_mfma(
    const unsigned short* __restrict__ Ah,
    const unsigned short* __restrict__ Al,
    const unsigned short* __restrict__ Bh,
    const unsigned short* __restrict__ Bl,
    const float* __restrict__ bias,
    const float* __restrict__ scale,
    const int* __restrict__ lists,
    const int* __restrict__ counts,
    float* __restrict__ C,
    unsigned short* __restrict__ Ch,
    unsigned short* __restrict__ Cl)
{
    __shared__ __align__(16) char sAh[8192];
    __shared__ __align__(16) char sAl[8192];
    __shared__ __align__(16) char sBh[8192];
    __shared__ __align__(16) char sBl[8192];
    __shared__ int Ts[128];

    const int tid = threadIdx.x;
    // block mapping: XCD-bijective swizzle, then y(n-tile)-fastest
    const int cpx = gridDim.x >> 3;               // 512->64, 544->68
    const int wg  = (blockIdx.x & 7) * cpx + (blockIdx.x >> 3);
    const int mt  = wg >> 2;
    const int n0  = (wg & 3) << 7;

    int listoff = 0, mcnt = 128;
    size_t boff = 0;
    const float* bb = bias;
    if constexpr (GATHER) {
        int acc8 = 0, eSel = -1, mstart = 0;
#pragma unroll
        for (int i = 0; i < 8; ++i) {
            const int c = counts[i];
            const int nt = (c + 127) >> 7;
            if (eSel < 0 && mt < acc8 + nt) { eSel = i; mstart = (mt - acc8) << 7; }
            acc8 += nt;
        }
        if (eSel < 0) return;
        mcnt = min(128, counts[eSel] - mstart);
        listoff = eSel * T_TOK + mstart;
        boff = (size_t)eSel << 18;
        bb = bias + (eSel << 9);
    }

    if (tid < 128) {
        int t;
        if constexpr (GATHER) t = (tid < mcnt) ? lists[listoff + tid] : -1;
        else                  t = (mt << 7) + tid;
        Ts[tid] = t;
    }
    __syncthreads();

    const int wid = tid >> 6, lane = tid & 63;

    // ---- staging: wave stages rows [wid*32, wid*32+32) of each buffer ----
    // lane -> (row delta, linear LDS granule); source granule = g ^ ((r>>1)&3)
    const int dr  = lane >> 2;                     // 0..15
    const int gsl = lane & 3;                      // linear granule slot
    const int r0 = (wid << 5) + dr, r1 = r0 + 16;
    const int gg0 = ((gsl ^ ((r0 >> 1) & 3)) & 3) << 4;
    const int gg1 = ((gsl ^ ((r1 >> 1) & 3)) & 3) << 4;
    const int tA0 = Ts[r0] < 0 ? 0 : Ts[r0];
    const int tA1 = Ts[r1] < 0 ? 0 : Ts[r1];
    const char* pah0 = (const char*)Ah + ((size_t)tA0 << 10) + gg0;
    const char* pah1 = (const char*)Ah + ((size_t)tA1 << 10) + gg1;
    const char* pal0 = (const char*)Al + ((size_t)tA0 << 10) + gg0;
    const char* pal1 = (const char*)Al + ((size_t)tA1 << 10) + gg1;
    const char* pbh0 = (const char*)(Bh + boff) + ((size_t)(n0 + r0) << 10) + gg0;
    const char* pbh1 = (const char*)(Bh + boff) + ((size_t)(n0 + r1) << 10) + gg1;
    const char* pbl0 = (const char*)(Bl + boff) + ((size_t)(n0 + r0) << 10) + gg0;
    const char* pbl1 = (const char*)(Bl + boff) + ((size_t)(n0 + r1) << 10) + gg1;
    char* const dA0 = sAh + (wid << 11); char* const dA1 = dA0 + 1024;
    char* const dL0 = sAl + (wid << 11); char* const dL1 = dL0 + 1024;
    char* const dB0 = sBh + (wid << 11); char* const dB1 = dB0 + 1024;
    char* const dC0 = sBl + (wid << 11); char* const dC1 = dC0 + 1024;

    // ---- wave / fragment ids ----
    const int wr = (wid >> 1) << 6;       // wave m-offset (0/64)
    const int wc = (wid & 1) << 6;        // wave n-offset (0/64)
    const int fr = lane & 15;
    const int fg = lane >> 4;             // k-granule 0..3

    f32x4 acc[4][4] = {};

#pragma unroll 1
    for (int kt = 0; kt < 16; ++kt) {
        __syncthreads();                  // previous K-step's LDS reads done
        gload16(pah0, dA0); gload16(pah1, dA1);
        gload16(pal0, dL0); gload16(pal1, dL1);
        gload16(pbh0, dB0); gload16(pbh1, dB1);
        gload16(pbl0, dC0); gload16(pbl1, dC1);
        pah0 += 64; pah1 += 64; pal0 += 64; pal1 += 64;
        pbh0 += 64; pbh1 += 64; pbl0 += 64; pbl1 += 64;
        __syncthreads();                  // vmcnt(0) drain -> LDS valid

        short8v a_h[4], a_l[4], b_h[4], b_l[4];
#pragma unroll
        for (int i = 0; i < 4; ++i) {
            const int r = wr + i * 16 + fr;
            a_h[i] = *(const short8v*)(sAh + swz(r, fg));
            a_l[i] = *(const short8v*)(sAl + swz(r, fg));
        }
#pragma unroll
        for (int j = 0; j < 4; ++j) {
            const int r = wc + j * 16 + fr;
            b_h[j] = *(const short8v*)(sBh + swz(r, fg));
            b_l[j] = *(const short8v*)(sBl + swz(r, fg));
        }
#pragma unroll
        for (int i = 0; i < 4; ++i)
#pragma unroll
            for (int j = 0; j < 4; ++j) {
                acc[i][j] = __builtin_amdgcn_mfma_f32_16x16x32_bf16(a_h[i], b_h[j], acc[i][j], 0, 0, 0);
                acc[i][j] = __builtin_amdgcn_mfma_f32_16x16x32_bf16(a_h[i], b_l[j], acc[i][j], 0, 0, 0);
                acc[i][j] = __builtin_amdgcn_mfma_f32_16x16x32_bf16(a_l[i], b_h[j], acc[i][j], 0, 0, 0);
            }
    }

    // ---- epilogue: bias (+ gate scale), fp32 + optional hi/lo stores ----
    float bj[4];
#pragma unroll
    for (int j = 0; j < 4; ++j) bj[j] = bb[n0 + wc + j * 16 + fr];
#pragma unroll
    for (int i = 0; i < 4; ++i) {
#pragma unroll
        for (int r = 0; r < 4; ++r) {
            const int m = wr + i * 16 + fg * 4 + r;   // C row = (lane>>4)*4 + reg
            const int t = Ts[m];
            if (t < 0) continue;
            float s = 1.f;
            if constexpr (GATHER) s = scale[t];
            const size_t rowo = (size_t)t * D + n0 + wc;
#pragma unroll
            for (int j = 0; j < 4; ++j) {
                const float v = (acc[i][j][r] + bj[j]) * s;
                const size_t o = rowo + j * 16 + fr;
                C[o] = v;
                if constexpr (OUTCONV) {
                    const unsigned short hv = f2bf(v);
                    Ch[o] = hv;
                    Cl[o] = f2bf(v - bf2f(hv));
                }
            }
        }
    }
}

// ---------------------------------------------------------------------------
// embed[b][f] += mean_s (h + out3);  grid (8, 64), 32 s per block
// ---------------------------------------------------------------------------
__global__ __launch_bounds__(256) void k_reduce(const float* __restrict__ H,
                                                const float* __restrict__ O3,
                                                float* __restrict__ embed)
{
    const int b = blockIdx.x;
    const int sc = blockIdx.y;
    const int f = threadIdx.x;
    const size_t base = ((size_t)b * 2048 + (size_t)sc * 32) * D;
    const float* hb = H + base;
    const float* ob = O3 + base;
    float a0 = 0.f, a1 = 0.f;
#pragma unroll 4
    for (int s = 0; s < 32; ++s) {
        a0 += hb[s * D + f]       + ob[s * D + f];
        a1 += hb[s * D + f + 256] + ob[s * D + f + 256];
    }
    atomicAdd(&embed[b * D + f],       a0 * (1.0f / 2048.0f));
    atomicAdd(&embed[b * D + f + 256], a1 * (1.0f / 2048.0f));
}

// ---------------------------------------------------------------------------
__global__ __launch_bounds__(512) void k_loss(const float* __restrict__ embed,
                                              const int* __restrict__ y,
                                              float* __restrict__ out)
{
    __shared__ float partial[8];
    const int w = threadIdx.x >> 6;
    const int lane = threadIdx.x & 63;
    const float* row = embed + w * D;

    float v[8];
    float vmax = -1e30f;
#pragma unroll
    for (int i = 0; i < 8; ++i) {
        v[i] = row[lane + i * 64];
        vmax = fmaxf(vmax, v[i]);
    }
#pragma unroll
    for (int o = 32; o > 0; o >>= 1) vmax = fmaxf(vmax, __shfl_xor(vmax, o));
    float s = 0.f;
#pragma unroll
    for (int i = 0; i < 8; ++i) s += expf(v[i] - vmax);
#pragma unroll
    for (int o = 32; o > 0; o >>= 1) s += __shfl_xor(s, o);
    const float lse = vmax + logf(s);
    if (lane == 0) partial[w] = lse - row[y[w]];
    __syncthreads();
    if (threadIdx.x == 0) {
        float l = 0.f;
#pragma unroll
        for (int b = 0; b < 8; ++b) l += partial[b];
        out[0] = l * (1.0f / 8.0f);
    }
}

// ---------------------------------------------------------------------------
extern "C" void kernel_launch(void* const* d_in, const int* in_sizes, int n_in,
                              void* d_out, int out_size, void* d_ws, size_t ws_size,
                              hipStream_t stream)
{
    const float* x   = (const float*)d_in[0];
    const float* W1  = (const float*)d_in[1];
    const float* b1  = (const float*)d_in[2];
    const float* gw2 = (const float*)d_in[3];
    const float* We2 = (const float*)d_in[4];
    const float* be2 = (const float*)d_in[5];
    const float* gw3 = (const float*)d_in[6];
    const float* We3 = (const float*)d_in[7];
    const float* be3 = (const float*)d_in[8];
    const int*   y   = (const int*)d_in[9];
    float* out = (float*)d_out;

    char* ws = (char*)d_ws;
    size_t off = 0;
    auto alloc = [&](size_t bytes) -> void* {
        void* p = ws + off;
        off = (off + bytes + 255) & ~(size_t)255;
        return p;
    };
    float* h     = (float*)alloc((size_t)T_TOK * D * 4);
    float* out2  = (float*)alloc((size_t)T_TOK * D * 4);
    float* out3  = (float*)alloc((size_t)T_TOK * D * 4);
    // xh/xl live only until GEMM-1; out3 written only by GEMM-3 -> overlap them
    unsigned short* xh = (unsigned short*)out3;
    unsigned short* xl = xh + (size_t)T_TOK * D;
    unsigned short* hh  = (unsigned short*)alloc((size_t)T_TOK * D * 2);
    unsigned short* hl  = (unsigned short*)alloc((size_t)T_TOK * D * 2);
    unsigned short* o2h = (unsigned short*)alloc((size_t)T_TOK * D * 2);
    unsigned short* o2l = (unsigned short*)alloc((size_t)T_TOK * D * 2);
    unsigned short* b1h  = (unsigned short*)alloc((size_t)D * D * 2);
    unsigned short* b1l  = (unsigned short*)alloc((size_t)D * D * 2);
    unsigned short* we2h = (unsigned short*)alloc((size_t)E * D * D * 2);
    unsigned short* we2l = (unsigned short*)alloc((size_t)E * D * D * 2);
    unsigned short* we3h = (unsigned short*)alloc((size_t)E * D * D * 2);
    unsigned short* we3l = (unsigned short*)alloc((size_t)E * D * D * 2);
    float* p2    = (float*)alloc((size_t)T_TOK * 4);
    float* p3    = (float*)alloc((size_t)T_TOK * 4);
    int*   l2    = (int*)alloc((size_t)E * T_TOK * 4);
    int*   l3    = (int*)alloc((size_t)E * T_TOK * 4);
    int*   c2    = (int*)alloc(E * 4);
    int*   c3    = (int*)alloc(E * 4);
    float* embed = (float*)alloc(8 * D * 4);
    (void)ws_size; (void)in_sizes; (void)n_in; (void)out_size;

    k_conv_w1<<<dim3(257), dim3(256), 0, stream>>>(W1, b1h, b1l, c2, c3, embed);
    k_prep_we<<<dim3(16, 16, 16), dim3(256), 0, stream>>>(We2, We3, we2h, we2l, we3h, we3l);
    k_conv_x<<<dim3(2048), dim3(256), 0, stream>>>(x, xh, xl);

    // h = x @ W1^T + b1   (also emits hh/hl for layer-2 A)
    k_gemm_mfma<false, true><<<dim3(512), dim3(256), 0, stream>>>(
        xh, xl, b1h, b1l, b1, nullptr, nullptr, nullptr, h, hh, hl);

    // MoE layer 2 (emits o2h/o2l for layer-3 A)
    k_gating<<<dim3(256), dim3(256), 0, stream>>>(h, gw2, p2, l2, c2);
    k_gemm_mfma<true, true><<<dim3(544), dim3(256), 0, stream>>>(
        hh, hl, we2h, we2l, be2, p2, l2, c2, out2, o2h, o2l);

    // MoE layer 3
    k_gating<<<dim3(256), dim3(256), 0, stream>>>(out2, gw3, p3, l3, c3);
    k_gemm_mfma<true, false><<<dim3(544), dim3(256), 0, stream>>>(
        o2h, o2l, we3h, we3l, be3, p3, l3, c3, out3, nullptr, nullptr);

    // hidden mean + loss
    k_reduce<<<dim3(8, 64), dim3(256), 0, stream>>>(h, out3, embed);
    k_loss<<<dim3(1), dim3(512), 0, stream>>>(embed, y, out);
}